// Round 3
// baseline (361.550 us; speedup 1.0000x reference)
//
#include <hip/hip_runtime.h>
#include <hip/hip_bf16.h>

typedef __bf16 bf16;
typedef __attribute__((ext_vector_type(8))) __bf16 bf16x8;
typedef __attribute__((ext_vector_type(4))) __bf16 bf16x4;
typedef __attribute__((ext_vector_type(4))) float floatx4;

#define MFMA16(a, b, c) __builtin_amdgcn_mfma_f32_16x16x32_bf16((a), (b), (c), 0, 0, 0)

#define DIM 384
#define T1 3136   // 56*56
#define T2 784    // 28*28
#define T2P 832   // padded t for Vt columns (13*64)
#define B_ 8
#define EPSV 1e-5f

__device__ __forceinline__ void gload_lds16(const bf16* g, bf16* l) {
  __builtin_amdgcn_global_load_lds(
      (const __attribute__((address_space(1))) void*)g,
      (__attribute__((address_space(3))) void*)l, 16, 0, 0);
}

// ---------------- depthwise conv + BN (q, stride 1), 4-wide x tiling ----------------
__global__ void conv_q_kernel(const float* __restrict__ x,
                              const float* __restrict__ wc,
                              const float* __restrict__ g, const float* __restrict__ bb,
                              const float* __restrict__ mm, const float* __restrict__ vv,
                              bf16* __restrict__ out) {
  int blk = blockIdx.x;          // xg + 14*(y + 56*b)
  int c = threadIdx.x;           // 0..383
  int xg = blk % 14;
  int y = (blk / 14) % 56;
  int b = blk / (14 * 56);
  int x0 = xg * 4;
  const float* xb = x + (size_t)b * T1 * DIM;
  float wr[9];
#pragma unroll
  for (int i = 0; i < 9; ++i) wr[i] = wc[c * 9 + i];
  float a = rsqrtf(vv[c] + EPSV) * g[c];
  float bia = bb[c] - mm[c] * a;
  float in[3][6];
#pragma unroll
  for (int r = 0; r < 3; ++r) {
    int yy = y + r - 1;
#pragma unroll
    for (int cc = 0; cc < 6; ++cc) {
      int xc = x0 + cc - 1;
      in[r][cc] = (yy >= 0 && yy < 56 && xc >= 0 && xc < 56)
                      ? xb[(yy * 56 + xc) * DIM + c] : 0.f;
    }
  }
#pragma unroll
  for (int p = 0; p < 4; ++p) {
    float s = 0.f;
#pragma unroll
    for (int r = 0; r < 3; ++r)
#pragma unroll
      for (int dx = 0; dx < 3; ++dx) s += in[r][p + dx] * wr[r * 3 + dx];
    out[((size_t)b * T1 + y * 56 + x0 + p) * DIM + c] = (bf16)(s * a + bia);
  }
}

// ---------------- depthwise conv + BN (k and v fused, stride 2), 4-wide ----------------
__global__ void conv_kv_kernel(const float* __restrict__ x,
    const float* __restrict__ wkc, const float* __restrict__ gk, const float* __restrict__ bk,
    const float* __restrict__ mk, const float* __restrict__ vk,
    const float* __restrict__ wvc, const float* __restrict__ gv, const float* __restrict__ bv,
    const float* __restrict__ mv, const float* __restrict__ vvv,
    bf16* __restrict__ kout, bf16* __restrict__ vout) {
  int blk = blockIdx.x;          // xg + 7*(y2 + 28*b)
  int c = threadIdx.x;
  int xg = blk % 7;
  int y2 = (blk / 7) % 28;
  int b = blk / (7 * 28);
  int x20 = xg * 4;
  const float* xb = x + (size_t)b * T1 * DIM;
  float wk9[9], wv9[9];
#pragma unroll
  for (int i = 0; i < 9; ++i) { wk9[i] = wkc[c * 9 + i]; wv9[i] = wvc[c * 9 + i]; }
  float ak = rsqrtf(vk[c] + EPSV) * gk[c];
  float av = rsqrtf(vvv[c] + EPSV) * gv[c];
  float bik = bk[c] - mk[c] * ak;
  float biv = bv[c] - mv[c] * av;
  float in[3][9];
  int y = 2 * y2;
#pragma unroll
  for (int r = 0; r < 3; ++r) {
    int yy = y + r - 1;
#pragma unroll
    for (int cc = 0; cc < 9; ++cc) {
      int xc = 2 * x20 + cc - 1;
      in[r][cc] = (yy >= 0 && yy < 56 && xc >= 0 && xc < 56)
                      ? xb[(yy * 56 + xc) * DIM + c] : 0.f;
    }
  }
#pragma unroll
  for (int p = 0; p < 4; ++p) {
    float sk = 0.f, sv = 0.f;
#pragma unroll
    for (int r = 0; r < 3; ++r)
#pragma unroll
      for (int dx = 0; dx < 3; ++dx) {
        float xv = in[r][2 * p + dx];
        sk += xv * wk9[r * 3 + dx];
        sv += xv * wv9[r * 3 + dx];
      }
    size_t o = ((size_t)b * T2 + y2 * 28 + x20 + p) * DIM + c;
    kout[o] = (bf16)(sk * ak + bik);
    vout[o] = (bf16)(sv * av + biv);
  }
}

// ---------------- fp32 -> bf16 weight conversion (4 matrices of 384x384) ----------------
__global__ void cvt4_kernel(const float* __restrict__ s0, const float* __restrict__ s1,
                            const float* __restrict__ s2, const float* __restrict__ s3,
                            bf16* __restrict__ d0, bf16* __restrict__ d1,
                            bf16* __restrict__ d2, bf16* __restrict__ d3) {
  int i = blockIdx.x * 256 + threadIdx.x;   // grid sized to exactly 384*384
  d0[i] = (bf16)s0[i];
  d1[i] = (bf16)s1[i];
  d2[i] = (bf16)s2[i];
  d3[i] = (bf16)s3[i];
}

// ---------------- bf16 GEMM: C[M,384] = A[M,384] @ W[384,384]^T ----------------
// m97-style: global_load_lds width=16 into unpadded [128][32] tiles.
// modes: 0/1 = bf16 out (x scale), 2 = transposed bf16 out Vt[b][n][t] stride T2P,
// 3 = fp32 out + bias.
#define BK 32
__global__ __launch_bounds__(256)
void gemm_bf16_kernel(const bf16* __restrict__ A, const bf16* __restrict__ Bw,
                      void* __restrict__ out, const float* __restrict__ bias,
                      int M, int mode, float scale) {
  __shared__ bf16 Al[128 * BK];
  __shared__ bf16 Bl[128 * BK];
  int tid = threadIdx.x;
  int m0 = blockIdx.x * 128, n0 = blockIdx.y * 128;
  int w = tid >> 6, lane = tid & 63;
  int wm = w >> 1, wn = w & 1;
  int l16 = lane & 15, quad = lane >> 4;
  floatx4 acc[4][4];
#pragma unroll
  for (int i = 0; i < 4; ++i)
#pragma unroll
    for (int j = 0; j < 4; ++j) acc[i][j] = (floatx4){0.f, 0.f, 0.f, 0.f};

  // staging: wave w stages rows w*32..w*32+31 of both A and B tiles.
  // lane -> (row = lane>>2, col16B = lane&3); LDS addr = base + lane*16.
  int srow = w * 32 + (lane >> 2);
  int scol = (lane & 3) * 8;
  const bf16* ag0 = &A[(size_t)(m0 + srow) * DIM + scol];
  const bf16* ag1 = ag0 + (size_t)16 * DIM;
  const bf16* bg0 = &Bw[(size_t)(n0 + srow) * DIM + scol];
  const bf16* bg1 = bg0 + (size_t)16 * DIM;
  bf16* la0 = &Al[(w * 32) * BK];
  bf16* la1 = &Al[(w * 32 + 16) * BK];
  bf16* lb0 = &Bl[(w * 32) * BK];
  bf16* lb1 = &Bl[(w * 32 + 16) * BK];

  for (int k0 = 0; k0 < DIM; k0 += BK) {
    __syncthreads();
    gload_lds16(ag0 + k0, la0);
    gload_lds16(ag1 + k0, la1);
    gload_lds16(bg0 + k0, lb0);
    gload_lds16(bg1 + k0, lb1);
    __syncthreads();
    bf16x8 af[4], bfr[4];
#pragma unroll
    for (int i = 0; i < 4; ++i) {
      af[i]  = *(const bf16x8*)&Al[(wm * 64 + i * 16 + l16) * BK + quad * 8];
      bfr[i] = *(const bf16x8*)&Bl[(wn * 64 + i * 16 + l16) * BK + quad * 8];
    }
#pragma unroll
    for (int i = 0; i < 4; ++i)
#pragma unroll
      for (int j = 0; j < 4; ++j)
        acc[i][j] = MFMA16(af[i], bfr[j], acc[i][j]);
  }
#pragma unroll
  for (int i = 0; i < 4; ++i) {
#pragma unroll
    for (int j = 0; j < 4; ++j) {
#pragma unroll
      for (int rr = 0; rr < 4; ++rr) {
        int row = m0 + wm * 64 + i * 16 + quad * 4 + rr;
        int col = n0 + wn * 64 + j * 16 + l16;
        float v = acc[i][j][rr];
        if (mode == 3) {
          ((float*)out)[(size_t)row * DIM + col] = v + bias[col];
        } else if (mode == 2) {
          int b = row / T2;
          int t = row - b * T2;
          ((bf16*)out)[((size_t)b * DIM + col) * T2P + t] = (bf16)v;
        } else {
          ((bf16*)out)[(size_t)row * DIM + col] = (bf16)(v * scale);
        }
      }
    }
  }
}

// ---------------- flash attention, S^T/O^T form, no-max softmax, barrier-free -------
// Block = 4 waves; wave = 32 q-rows (2 q-tiles); block = 128 q of one (b,h).
// K/V fragments loaded directly from global (L1-resident 16 KB/iter working set).
// P round-trips wave-private LDS (same-wave DS ordering => no barriers anywhere).
// Qp pre-scaled by SCALE*log2e; p = exp2(s). 12 clean KV iters + peeled tail.
#define PLDS 72   // P row stride in shorts
__global__ __launch_bounds__(256, 3)
void attn_kernel(const bf16* __restrict__ Qp, const bf16* __restrict__ Kp,
                 const bf16* __restrict__ Vt, bf16* __restrict__ Ob) {
  __shared__ bf16 Pl[4][2][16 * PLDS];    // per-wave, per-qtile [q][t]
  int blk = blockIdx.x;
  int qblk = blk % 25;
  int h = (blk / 25) % 6;
  int b = blk / (25 * 6);
  int tid = threadIdx.x, w = tid >> 6, lane = tid & 63;
  int l16 = lane & 15, quad = lane >> 4;
  int q0w = qblk * 128 + w * 32;

  // Q fragments (B-operand layout: n = lane&15, k = quad*8+j); clamp OOB rows
  bf16x8 qf[2][2];
#pragma unroll
  for (int qt = 0; qt < 2; ++qt) {
    int qi = q0w + qt * 16 + l16;
    qi = qi < T1 ? qi : T1 - 1;
    const bf16* qp = &Qp[((size_t)b * T1 + qi) * DIM + h * 64];
    qf[qt][0] = *(const bf16x8*)&qp[quad * 8];
    qf[qt][1] = *(const bf16x8*)&qp[32 + quad * 8];
  }
  floatx4 oacc[2][4];
#pragma unroll
  for (int qt = 0; qt < 2; ++qt)
#pragma unroll
    for (int dt = 0; dt < 4; ++dt) oacc[qt][dt] = (floatx4){0.f, 0.f, 0.f, 0.f};
  float lsum[2] = {0.f, 0.f};

  // per-lane global fragment pointers (advance by 64 t per iter)
  const bf16* kptr = &Kp[((size_t)b * T2 + l16) * DIM + h * 64 + quad * 8];
  const bf16* vptr = &Vt[((size_t)b * DIM + h * 64 + l16) * T2P + quad * 8];
  bf16* pw0 = &Pl[w][0][l16 * PLDS + quad * 4];
  bf16* pr0 = &Pl[w][0][l16 * PLDS + quad * 8];

  for (int it = 0; it < 12; ++it) {
    // load all K fragments for this 64-t tile
    bf16x8 kf[4][2];
#pragma unroll
    for (int mt = 0; mt < 4; ++mt) {
      kf[mt][0] = *(const bf16x8*)(kptr + (size_t)mt * 16 * DIM);
      kf[mt][1] = *(const bf16x8*)(kptr + (size_t)mt * 16 * DIM + 32);
    }
#pragma unroll
    for (int mt = 0; mt < 4; ++mt) {
#pragma unroll
      for (int qt = 0; qt < 2; ++qt) {
        floatx4 z = (floatx4){0.f, 0.f, 0.f, 0.f};
        z = MFMA16(kf[mt][0], qf[qt][0], z);
        z = MFMA16(kf[mt][1], qf[qt][1], z);
        float p0 = __builtin_amdgcn_exp2f(z[0]);
        float p1 = __builtin_amdgcn_exp2f(z[1]);
        float p2 = __builtin_amdgcn_exp2f(z[2]);
        float p3 = __builtin_amdgcn_exp2f(z[3]);
        lsum[qt] += (p0 + p1) + (p2 + p3);
        bf16x4 pw = (bf16x4){(bf16)p0, (bf16)p1, (bf16)p2, (bf16)p3};
        *(bf16x4*)(pw0 + qt * 16 * PLDS + mt * 16) = pw;
      }
    }
    // O^T += V^T P^T
#pragma unroll
    for (int kt = 0; kt < 2; ++kt) {
      bf16x8 pf0 = *(const bf16x8*)(pr0 + kt * 32);
      bf16x8 pf1 = *(const bf16x8*)(pr0 + 16 * PLDS + kt * 32);
#pragma unroll
      for (int dt = 0; dt < 4; ++dt) {
        bf16x8 vf = *(const bf16x8*)(vptr + (size_t)dt * 16 * T2P + kt * 32);
        oacc[0][dt] = MFMA16(vf, pf0, oacc[0][dt]);
        oacc[1][dt] = MFMA16(vf, pf1, oacc[1][dt]);
      }
    }
    kptr += (size_t)64 * DIM;
    vptr += 64;
  }
  // tail: t 768..783 valid (mt 0 only); zero mt1; PV over kt=0 only
  {
    bf16x8 kf0 = *(const bf16x8*)(kptr);
    bf16x8 kf1 = *(const bf16x8*)(kptr + 32);
    bf16x4 zz = (bf16x4){(bf16)0.f, (bf16)0.f, (bf16)0.f, (bf16)0.f};
#pragma unroll
    for (int qt = 0; qt < 2; ++qt) {
      floatx4 z = (floatx4){0.f, 0.f, 0.f, 0.f};
      z = MFMA16(kf0, qf[qt][0], z);
      z = MFMA16(kf1, qf[qt][1], z);
      float p0 = __builtin_amdgcn_exp2f(z[0]);
      float p1 = __builtin_amdgcn_exp2f(z[1]);
      float p2 = __builtin_amdgcn_exp2f(z[2]);
      float p3 = __builtin_amdgcn_exp2f(z[3]);
      lsum[qt] += (p0 + p1) + (p2 + p3);
      bf16x4 pw = (bf16x4){(bf16)p0, (bf16)p1, (bf16)p2, (bf16)p3};
      *(bf16x4*)(pw0 + qt * 16 * PLDS) = pw;
      *(bf16x4*)(pw0 + qt * 16 * PLDS + 16) = zz;   // mt1 zeros (read by kt=0)
    }
    bf16x8 pf0 = *(const bf16x8*)(pr0);
    bf16x8 pf1 = *(const bf16x8*)(pr0 + 16 * PLDS);
#pragma unroll
    for (int dt = 0; dt < 4; ++dt) {
      bf16x8 vf = *(const bf16x8*)(vptr + (size_t)dt * 16 * T2P);
      oacc[0][dt] = MFMA16(vf, pf0, oacc[0][dt]);
      oacc[1][dt] = MFMA16(vf, pf1, oacc[1][dt]);
    }
  }
  // epilogue: reduce l across quads, scale, pack 4 bf16 -> 8B stores
#pragma unroll
  for (int qt = 0; qt < 2; ++qt) {
    float l = lsum[qt];
    l += __shfl_xor(l, 16);
    l += __shfl_xor(l, 32);
    float inv = 1.f / l;
    int qg = q0w + qt * 16 + l16;
    if (qg < T1) {
      bf16* op = &Ob[((size_t)b * T1 + qg) * DIM + h * 64];
#pragma unroll
      for (int dt = 0; dt < 4; ++dt) {
        floatx4 o = oacc[qt][dt];
        bf16x4 ov = (bf16x4){(bf16)(o[0] * inv), (bf16)(o[1] * inv),
                             (bf16)(o[2] * inv), (bf16)(o[3] * inv)};
        *(bf16x4*)&op[dt * 16 + quad * 4] = ov;
      }
    }
  }
}

// ---------------- launch ----------------
extern "C" void kernel_launch(void* const* d_in, const int* in_sizes, int n_in,
                              void* d_out, int out_size, void* d_ws, size_t ws_size,
                              hipStream_t stream) {
  (void)in_sizes; (void)n_in; (void)out_size; (void)ws_size;
  const float* x      = (const float*)d_in[0];
  const float* conv_q = (const float*)d_in[3];
  const float* bnq_s  = (const float*)d_in[4];
  const float* bnq_b  = (const float*)d_in[5];
  const float* bnq_m  = (const float*)d_in[6];
  const float* bnq_v  = (const float*)d_in[7];
  const float* conv_k = (const float*)d_in[8];
  const float* bnk_s  = (const float*)d_in[9];
  const float* bnk_b  = (const float*)d_in[10];
  const float* bnk_m  = (const float*)d_in[11];
  const float* bnk_v  = (const float*)d_in[12];
  const float* conv_v = (const float*)d_in[13];
  const float* bnv_s  = (const float*)d_in[14];
  const float* bnv_b  = (const float*)d_in[15];
  const float* bnv_m  = (const float*)d_in[16];
  const float* bnv_v  = (const float*)d_in[17];
  const float* wq     = (const float*)d_in[18];
  const float* wk     = (const float*)d_in[19];
  const float* wv     = (const float*)d_in[20];
  const float* wl     = (const float*)d_in[21];
  const float* b_last = (const float*)d_in[22];

  char* ws = (char*)d_ws;
  bf16* q_act = (bf16*)(ws + 0);               // 19267584; reused as attention output
  bf16* k_act = (bf16*)(ws + 19267584);        // 4816896
  bf16* v_act = (bf16*)(ws + 24084480);        // 4816896
  bf16* Qp    = (bf16*)(ws + 28901376);        // 19267584 (pre-scaled by SCALE*log2e)
  bf16* Kp    = (bf16*)(ws + 48168960);        // 4816896
  bf16* Vtp   = (bf16*)(ws + 52985856);        // 8*384*832*2 = 5111808  [B][384][T2P]
  bf16* wqb   = (bf16*)(ws + 58097664);        // 294912 each, x4
  bf16* wkb   = wqb + 147456;
  bf16* wvb   = wkb + 147456;
  bf16* wlb   = wvb + 147456;

  const float QSCALE = 0.05103103630798288f * 1.4426950408889634f;  // 384^-0.5 * log2(e)

  conv_q_kernel<<<B_ * 56 * 14, DIM, 0, stream>>>(x, conv_q, bnq_s, bnq_b, bnq_m, bnq_v, q_act);
  conv_kv_kernel<<<B_ * 28 * 7, DIM, 0, stream>>>(x, conv_k, bnk_s, bnk_b, bnk_m, bnk_v,
                                                  conv_v, bnv_s, bnv_b, bnv_m, bnv_v,
                                                  k_act, v_act);
  cvt4_kernel<<<576, 256, 0, stream>>>(wq, wk, wv, wl, wqb, wkb, wvb, wlb);

  gemm_bf16_kernel<<<dim3(196, 3), 256, 0, stream>>>(q_act, wqb, Qp, nullptr,
                                                     B_ * T1, 1, QSCALE);
  gemm_bf16_kernel<<<dim3(49, 3), 256, 0, stream>>>(k_act, wkb, Kp, nullptr,
                                                    B_ * T2, 0, 1.f);
  gemm_bf16_kernel<<<dim3(49, 3), 256, 0, stream>>>(v_act, wvb, Vtp, nullptr,
                                                    B_ * T2, 2, 1.f);

  attn_kernel<<<25 * 6 * B_, 256, 0, stream>>>(Qp, Kp, Vtp, q_act);

  gemm_bf16_kernel<<<dim3(196, 3), 256, 0, stream>>>(q_act, wlb, d_out, b_last,
                                                     B_ * T1, 3, 1.f);
}

// Round 4
// 281.097 us; speedup vs baseline: 1.2862x; 1.2862x over previous
//
#include <hip/hip_runtime.h>
#include <hip/hip_bf16.h>

typedef __bf16 bf16;
typedef __attribute__((ext_vector_type(8))) __bf16 bf16x8;
typedef __attribute__((ext_vector_type(4))) __bf16 bf16x4;
typedef __attribute__((ext_vector_type(4))) float floatx4;

#define MFMA16(a, b, c) __builtin_amdgcn_mfma_f32_16x16x32_bf16((a), (b), (c), 0, 0, 0)

#define DIM 384
#define T1 3136   // 56*56
#define T2 784    // 28*28
#define T2P 832   // padded t for Vt columns (13*64)
#define B_ 8
#define EPSV 1e-5f

__device__ __forceinline__ void gload_lds16(const bf16* g, bf16* l) {
  __builtin_amdgcn_global_load_lds(
      (const __attribute__((address_space(1))) void*)g,
      (__attribute__((address_space(3))) void*)l, 16, 0, 0);
}

// ---------------- depthwise conv + BN (q, stride 1), 4-wide x tiling ----------------
__global__ void conv_q_kernel(const float* __restrict__ x,
                              const float* __restrict__ wc,
                              const float* __restrict__ g, const float* __restrict__ bb,
                              const float* __restrict__ mm, const float* __restrict__ vv,
                              bf16* __restrict__ out) {
  int blk = blockIdx.x;          // xg + 14*(y + 56*b)
  int c = threadIdx.x;           // 0..383
  int xg = blk % 14;
  int y = (blk / 14) % 56;
  int b = blk / (14 * 56);
  int x0 = xg * 4;
  const float* xb = x + (size_t)b * T1 * DIM;
  float wr[9];
#pragma unroll
  for (int i = 0; i < 9; ++i) wr[i] = wc[c * 9 + i];
  float a = rsqrtf(vv[c] + EPSV) * g[c];
  float bia = bb[c] - mm[c] * a;
  float in[3][6];
#pragma unroll
  for (int r = 0; r < 3; ++r) {
    int yy = y + r - 1;
#pragma unroll
    for (int cc = 0; cc < 6; ++cc) {
      int xc = x0 + cc - 1;
      in[r][cc] = (yy >= 0 && yy < 56 && xc >= 0 && xc < 56)
                      ? xb[(yy * 56 + xc) * DIM + c] : 0.f;
    }
  }
#pragma unroll
  for (int p = 0; p < 4; ++p) {
    float s = 0.f;
#pragma unroll
    for (int r = 0; r < 3; ++r)
#pragma unroll
      for (int dx = 0; dx < 3; ++dx) s += in[r][p + dx] * wr[r * 3 + dx];
    out[((size_t)b * T1 + y * 56 + x0 + p) * DIM + c] = (bf16)(s * a + bia);
  }
}

// ---------------- depthwise conv + BN (k and v fused, stride 2), 4-wide ----------------
__global__ void conv_kv_kernel(const float* __restrict__ x,
    const float* __restrict__ wkc, const float* __restrict__ gk, const float* __restrict__ bk,
    const float* __restrict__ mk, const float* __restrict__ vk,
    const float* __restrict__ wvc, const float* __restrict__ gv, const float* __restrict__ bv,
    const float* __restrict__ mv, const float* __restrict__ vvv,
    bf16* __restrict__ kout, bf16* __restrict__ vout) {
  int blk = blockIdx.x;          // xg + 7*(y2 + 28*b)
  int c = threadIdx.x;
  int xg = blk % 7;
  int y2 = (blk / 7) % 28;
  int b = blk / (7 * 28);
  int x20 = xg * 4;
  const float* xb = x + (size_t)b * T1 * DIM;
  float wk9[9], wv9[9];
#pragma unroll
  for (int i = 0; i < 9; ++i) { wk9[i] = wkc[c * 9 + i]; wv9[i] = wvc[c * 9 + i]; }
  float ak = rsqrtf(vk[c] + EPSV) * gk[c];
  float av = rsqrtf(vvv[c] + EPSV) * gv[c];
  float bik = bk[c] - mk[c] * ak;
  float biv = bv[c] - mv[c] * av;
  float in[3][9];
  int y = 2 * y2;
#pragma unroll
  for (int r = 0; r < 3; ++r) {
    int yy = y + r - 1;
#pragma unroll
    for (int cc = 0; cc < 9; ++cc) {
      int xc = 2 * x20 + cc - 1;
      in[r][cc] = (yy >= 0 && yy < 56 && xc >= 0 && xc < 56)
                      ? xb[(yy * 56 + xc) * DIM + c] : 0.f;
    }
  }
#pragma unroll
  for (int p = 0; p < 4; ++p) {
    float sk = 0.f, sv = 0.f;
#pragma unroll
    for (int r = 0; r < 3; ++r)
#pragma unroll
      for (int dx = 0; dx < 3; ++dx) {
        float xv = in[r][2 * p + dx];
        sk += xv * wk9[r * 3 + dx];
        sv += xv * wv9[r * 3 + dx];
      }
    size_t o = ((size_t)b * T2 + y2 * 28 + x20 + p) * DIM + c;
    kout[o] = (bf16)(sk * ak + bik);
    vout[o] = (bf16)(sv * av + biv);
  }
}

// ---------------- fp32 -> bf16 weight conversion (4 matrices of 384x384) ----------------
__global__ void cvt4_kernel(const float* __restrict__ s0, const float* __restrict__ s1,
                            const float* __restrict__ s2, const float* __restrict__ s3,
                            bf16* __restrict__ d0, bf16* __restrict__ d1,
                            bf16* __restrict__ d2, bf16* __restrict__ d3) {
  int i = blockIdx.x * 256 + threadIdx.x;   // grid sized to exactly 384*384
  d0[i] = (bf16)s0[i];
  d1[i] = (bf16)s1[i];
  d2[i] = (bf16)s2[i];
  d3[i] = (bf16)s3[i];
}

// ---------------- bf16 GEMM: C[M,384] = A[M,384] @ W[384,384]^T ----------------
// m97-style: global_load_lds width=16 into unpadded [128][32] tiles.
#define BK 32
__global__ __launch_bounds__(256)
void gemm_bf16_kernel(const bf16* __restrict__ A, const bf16* __restrict__ Bw,
                      void* __restrict__ out, const float* __restrict__ bias,
                      int M, int mode, float scale) {
  __shared__ bf16 Al[128 * BK];
  __shared__ bf16 Bl[128 * BK];
  int tid = threadIdx.x;
  int m0 = blockIdx.x * 128, n0 = blockIdx.y * 128;
  int w = tid >> 6, lane = tid & 63;
  int wm = w >> 1, wn = w & 1;
  int l16 = lane & 15, quad = lane >> 4;
  floatx4 acc[4][4];
#pragma unroll
  for (int i = 0; i < 4; ++i)
#pragma unroll
    for (int j = 0; j < 4; ++j) acc[i][j] = (floatx4){0.f, 0.f, 0.f, 0.f};

  int srow = w * 32 + (lane >> 2);
  int scol = (lane & 3) * 8;
  const bf16* ag0 = &A[(size_t)(m0 + srow) * DIM + scol];
  const bf16* ag1 = ag0 + (size_t)16 * DIM;
  const bf16* bg0 = &Bw[(size_t)(n0 + srow) * DIM + scol];
  const bf16* bg1 = bg0 + (size_t)16 * DIM;
  bf16* la0 = &Al[(w * 32) * BK];
  bf16* la1 = &Al[(w * 32 + 16) * BK];
  bf16* lb0 = &Bl[(w * 32) * BK];
  bf16* lb1 = &Bl[(w * 32 + 16) * BK];

  for (int k0 = 0; k0 < DIM; k0 += BK) {
    __syncthreads();
    gload_lds16(ag0 + k0, la0);
    gload_lds16(ag1 + k0, la1);
    gload_lds16(bg0 + k0, lb0);
    gload_lds16(bg1 + k0, lb1);
    __syncthreads();
    bf16x8 af[4], bfr[4];
#pragma unroll
    for (int i = 0; i < 4; ++i) {
      af[i]  = *(const bf16x8*)&Al[(wm * 64 + i * 16 + l16) * BK + quad * 8];
      bfr[i] = *(const bf16x8*)&Bl[(wn * 64 + i * 16 + l16) * BK + quad * 8];
    }
#pragma unroll
    for (int i = 0; i < 4; ++i)
#pragma unroll
      for (int j = 0; j < 4; ++j)
        acc[i][j] = MFMA16(af[i], bfr[j], acc[i][j]);
  }
#pragma unroll
  for (int i = 0; i < 4; ++i) {
#pragma unroll
    for (int j = 0; j < 4; ++j) {
#pragma unroll
      for (int rr = 0; rr < 4; ++rr) {
        int row = m0 + wm * 64 + i * 16 + quad * 4 + rr;
        int col = n0 + wn * 64 + j * 16 + l16;
        float v = acc[i][j][rr];
        if (mode == 3) {
          ((float*)out)[(size_t)row * DIM + col] = v + bias[col];
        } else if (mode == 2) {
          int b = row / T2;
          int t = row - b * T2;
          ((bf16*)out)[((size_t)b * DIM + col) * T2P + t] = (bf16)v;
        } else {
          ((bf16*)out)[(size_t)row * DIM + col] = (bf16)(v * scale);
        }
      }
    }
  }
}

// ---------------- flash attention, S^T/O^T form, no-max softmax -------------------
// Block = 4 waves, 128 q of one (b,h); wave = 32 q (2 q-tiles of 16).
// K[64t][64d] and V^T[64d][64t] tiles staged ONCE per block per iter via
// global_load_lds (width 16), with chunk-XOR swizzle so the b128 fragment reads
// are bank-conflict-free despite the 128 B row stride.  m97 2-barrier loop.
// P round-trips wave-private LDS (same-wave DS ordering => no barrier).
// Qp pre-scaled by SCALE*log2e; p = exp2(s). 12 staged iters + peeled direct tail.
#define PLDS 72   // P row stride in shorts
__global__ __launch_bounds__(256, 4)
void attn_kernel(const bf16* __restrict__ Qp, const bf16* __restrict__ Kp,
                 const bf16* __restrict__ Vt, bf16* __restrict__ Ob) {
  __shared__ bf16 Kl[64 * 64];            // [t][d], swizzled chunks
  __shared__ bf16 Vl[64 * 64];            // [d][t], swizzled chunks
  __shared__ bf16 Pl[4][2][16 * PLDS];    // per-wave, per-qtile [q][t]
  int blk = blockIdx.x;
  int qblk = blk % 25;
  int h = (blk / 25) % 6;
  int b = blk / (25 * 6);
  int tid = threadIdx.x, w = tid >> 6, lane = tid & 63;
  int l16 = lane & 15, quad = lane >> 4;
  int q0w = qblk * 128 + w * 32;

  // Q fragments (B-operand layout: n = lane&15, k = quad*8+j); clamp OOB rows
  bf16x8 qf[2][2];
#pragma unroll
  for (int qt = 0; qt < 2; ++qt) {
    int qi = q0w + qt * 16 + l16;
    qi = qi < T1 ? qi : T1 - 1;
    const bf16* qp = &Qp[((size_t)b * T1 + qi) * DIM + h * 64];
    qf[qt][0] = *(const bf16x8*)&qp[quad * 8];
    qf[qt][1] = *(const bf16x8*)&qp[32 + quad * 8];
  }
  floatx4 oacc[2][4];
#pragma unroll
  for (int qt = 0; qt < 2; ++qt)
#pragma unroll
    for (int dt = 0; dt < 4; ++dt) oacc[qt][dt] = (floatx4){0.f, 0.f, 0.f, 0.f};
  float lsum[2] = {0.f, 0.f};

  // staging source/dest: one instr = 8 rows x 128 B; lane -> (row=lane>>3, chunk=lane&7),
  // source chunk swizzled by row&7 (== lane>>3 since row groups are 8-aligned).
  int rsub = lane >> 3;                       // 0..7
  int chnk = (lane & 7) ^ rsub;               // swizzled source chunk
  const bf16* kg0 = &Kp[((size_t)b * T2 + w * 16 + rsub) * DIM + h * 64 + chnk * 8];
  const bf16* kg1 = kg0 + (size_t)8 * DIM;
  const bf16* vg0 = &Vt[((size_t)b * DIM + h * 64 + w * 16 + rsub) * T2P + chnk * 8];
  const bf16* vg1 = vg0 + (size_t)8 * T2P;
  bf16* kl0 = &Kl[(w * 16) * 64];
  bf16* kl1 = &Kl[(w * 16 + 8) * 64];
  bf16* vl0 = &Vl[(w * 16) * 64];
  bf16* vl1 = &Vl[(w * 16 + 8) * 64];

  // fragment-read swizzle offsets (loop-invariant)
  int sw = l16 & 7;
  bf16* pw0 = &Pl[w][0][l16 * PLDS + quad * 4];
  bf16* pr0 = &Pl[w][0][l16 * PLDS + quad * 8];

  for (int it = 0; it < 12; ++it) {
    __syncthreads();                          // prev iter's tile reads done
    gload_lds16(kg0, kl0);
    gload_lds16(kg1, kl1);
    gload_lds16(vg0, vl0);
    gload_lds16(vg1, vl1);
    __syncthreads();                          // drains vmcnt: tiles ready
    // S^T = K Q^T per (mt, qt)
#pragma unroll
    for (int mt = 0; mt < 4; ++mt) {
      int krow = (mt * 16 + l16) * 64;
      bf16x8 kf0 = *(const bf16x8*)&Kl[krow + ((quad) ^ sw) * 8];
      bf16x8 kf1 = *(const bf16x8*)&Kl[krow + ((quad + 4) ^ sw) * 8];
#pragma unroll
      for (int qt = 0; qt < 2; ++qt) {
        floatx4 z = (floatx4){0.f, 0.f, 0.f, 0.f};
        z = MFMA16(kf0, qf[qt][0], z);
        z = MFMA16(kf1, qf[qt][1], z);
        float p0 = __builtin_amdgcn_exp2f(z[0]);
        float p1 = __builtin_amdgcn_exp2f(z[1]);
        float p2 = __builtin_amdgcn_exp2f(z[2]);
        float p3 = __builtin_amdgcn_exp2f(z[3]);
        lsum[qt] += (p0 + p1) + (p2 + p3);
        bf16x4 pw = (bf16x4){(bf16)p0, (bf16)p1, (bf16)p2, (bf16)p3};
        *(bf16x4*)(pw0 + qt * 16 * PLDS + mt * 16) = pw;
      }
    }
    // O^T += V^T P^T
#pragma unroll
    for (int kt = 0; kt < 2; ++kt) {
      bf16x8 pf0 = *(const bf16x8*)(pr0 + kt * 32);
      bf16x8 pf1 = *(const bf16x8*)(pr0 + 16 * PLDS + kt * 32);
#pragma unroll
      for (int dt = 0; dt < 4; ++dt) {
        bf16x8 vf = *(const bf16x8*)&Vl[(dt * 16 + l16) * 64 + ((kt * 4 + quad) ^ sw) * 8];
        oacc[0][dt] = MFMA16(vf, pf0, oacc[0][dt]);
        oacc[1][dt] = MFMA16(vf, pf1, oacc[1][dt]);
      }
    }
    kg0 += (size_t)64 * DIM; kg1 += (size_t)64 * DIM;
    vg0 += 64; vg1 += 64;
  }
  // tail: t 768..783 (direct global fragment loads; mt0 only, zero mt1, kt=0 PV)
  {
    const bf16* kptr = &Kp[((size_t)b * T2 + 768 + l16) * DIM + h * 64 + quad * 8];
    const bf16* vptr = &Vt[((size_t)b * DIM + h * 64 + l16) * T2P + 768 + quad * 8];
    bf16x8 kf0 = *(const bf16x8*)(kptr);
    bf16x8 kf1 = *(const bf16x8*)(kptr + 32);
    bf16x4 zz = (bf16x4){(bf16)0.f, (bf16)0.f, (bf16)0.f, (bf16)0.f};
#pragma unroll
    for (int qt = 0; qt < 2; ++qt) {
      floatx4 z = (floatx4){0.f, 0.f, 0.f, 0.f};
      z = MFMA16(kf0, qf[qt][0], z);
      z = MFMA16(kf1, qf[qt][1], z);
      float p0 = __builtin_amdgcn_exp2f(z[0]);
      float p1 = __builtin_amdgcn_exp2f(z[1]);
      float p2 = __builtin_amdgcn_exp2f(z[2]);
      float p3 = __builtin_amdgcn_exp2f(z[3]);
      lsum[qt] += (p0 + p1) + (p2 + p3);
      bf16x4 pw = (bf16x4){(bf16)p0, (bf16)p1, (bf16)p2, (bf16)p3};
      *(bf16x4*)(pw0 + qt * 16 * PLDS) = pw;
      *(bf16x4*)(pw0 + qt * 16 * PLDS + 16) = zz;
    }
    bf16x8 pf0 = *(const bf16x8*)(pr0);
    bf16x8 pf1 = *(const bf16x8*)(pr0 + 16 * PLDS);
#pragma unroll
    for (int dt = 0; dt < 4; ++dt) {
      bf16x8 vf = *(const bf16x8*)(vptr + (size_t)dt * 16 * T2P);
      oacc[0][dt] = MFMA16(vf, pf0, oacc[0][dt]);
      oacc[1][dt] = MFMA16(vf, pf1, oacc[1][dt]);
    }
  }
  // epilogue: reduce l across quads, scale, pack 4 bf16 -> 8B stores
#pragma unroll
  for (int qt = 0; qt < 2; ++qt) {
    float l = lsum[qt];
    l += __shfl_xor(l, 16);
    l += __shfl_xor(l, 32);
    float inv = 1.f / l;
    int qg = q0w + qt * 16 + l16;
    if (qg < T1) {
      bf16* op = &Ob[((size_t)b * T1 + qg) * DIM + h * 64];
#pragma unroll
      for (int dt = 0; dt < 4; ++dt) {
        floatx4 o = oacc[qt][dt];
        bf16x4 ov = (bf16x4){(bf16)(o[0] * inv), (bf16)(o[1] * inv),
                             (bf16)(o[2] * inv), (bf16)(o[3] * inv)};
        *(bf16x4*)&op[dt * 16 + quad * 4] = ov;
      }
    }
  }
}

// ---------------- launch ----------------
extern "C" void kernel_launch(void* const* d_in, const int* in_sizes, int n_in,
                              void* d_out, int out_size, void* d_ws, size_t ws_size,
                              hipStream_t stream) {
  (void)in_sizes; (void)n_in; (void)out_size; (void)ws_size;
  const float* x      = (const float*)d_in[0];
  const float* conv_q = (const float*)d_in[3];
  const float* bnq_s  = (const float*)d_in[4];
  const float* bnq_b  = (const float*)d_in[5];
  const float* bnq_m  = (const float*)d_in[6];
  const float* bnq_v  = (const float*)d_in[7];
  const float* conv_k = (const float*)d_in[8];
  const float* bnk_s  = (const float*)d_in[9];
  const float* bnk_b  = (const float*)d_in[10];
  const float* bnk_m  = (const float*)d_in[11];
  const float* bnk_v  = (const float*)d_in[12];
  const float* conv_v = (const float*)d_in[13];
  const float* bnv_s  = (const float*)d_in[14];
  const float* bnv_b  = (const float*)d_in[15];
  const float* bnv_m  = (const float*)d_in[16];
  const float* bnv_v  = (const float*)d_in[17];
  const float* wq     = (const float*)d_in[18];
  const float* wk     = (const float*)d_in[19];
  const float* wv     = (const float*)d_in[20];
  const float* wl     = (const float*)d_in[21];
  const float* b_last = (const float*)d_in[22];

  char* ws = (char*)d_ws;
  bf16* q_act = (bf16*)(ws + 0);               // 19267584; reused as attention output
  bf16* k_act = (bf16*)(ws + 19267584);        // 4816896
  bf16* v_act = (bf16*)(ws + 24084480);        // 4816896
  bf16* Qp    = (bf16*)(ws + 28901376);        // 19267584 (pre-scaled by SCALE*log2e)
  bf16* Kp    = (bf16*)(ws + 48168960);        // 4816896
  bf16* Vtp   = (bf16*)(ws + 52985856);        // 8*384*832*2 = 5111808  [B][384][T2P]
  bf16* wqb   = (bf16*)(ws + 58097664);        // 294912 each, x4
  bf16* wkb   = wqb + 147456;
  bf16* wvb   = wkb + 147456;
  bf16* wlb   = wvb + 147456;

  const float QSCALE = 0.05103103630798288f * 1.4426950408889634f;  // 384^-0.5 * log2(e)

  conv_q_kernel<<<B_ * 56 * 14, DIM, 0, stream>>>(x, conv_q, bnq_s, bnq_b, bnq_m, bnq_v, q_act);
  conv_kv_kernel<<<B_ * 28 * 7, DIM, 0, stream>>>(x, conv_k, bnk_s, bnk_b, bnk_m, bnk_v,
                                                  conv_v, bnv_s, bnv_b, bnv_m, bnv_v,
                                                  k_act, v_act);
  cvt4_kernel<<<576, 256, 0, stream>>>(wq, wk, wv, wl, wqb, wkb, wvb, wlb);

  gemm_bf16_kernel<<<dim3(196, 3), 256, 0, stream>>>(q_act, wqb, Qp, nullptr,
                                                     B_ * T1, 1, QSCALE);
  gemm_bf16_kernel<<<dim3(49, 3), 256, 0, stream>>>(k_act, wkb, Kp, nullptr,
                                                    B_ * T2, 0, 1.f);
  gemm_bf16_kernel<<<dim3(49, 3), 256, 0, stream>>>(v_act, wvb, Vtp, nullptr,
                                                    B_ * T2, 2, 1.f);

  attn_kernel<<<25 * 6 * B_, 256, 0, stream>>>(Qp, Kp, Vtp, q_act);

  gemm_bf16_kernel<<<dim3(196, 3), 256, 0, stream>>>(q_act, wlb, d_out, b_last,
                                                     B_ * T1, 3, 1.f);
}